// Round 2
// baseline (368.552 us; speedup 1.0000x reference)
//
#include <hip/hip_runtime.h>
#include <math.h>

#define G      1708
#define NH     5
#define NB     16
#define NC     34
#define NCH    427          // float4 chunks per gene row (1708/4)
#define IPB    32           // i-values per block
#define JSL    8            // j-slices per i  (IPB*JSL = 256 threads)
#define LN_EPS 1e-6f
#define LOG2E  1.4426950408889634f

// ---------------------------------------------------------------------------
// Attention layer: out[b,i] = sum_h W0[h] * (S2 - e_ii*v_i) / S1   with
//   S1 = sum_j exp(s_ij - m_i), S2 = sum_j exp(s_ij - m_i) v_j,
//   s_ij = q_i k_j,  m_i = max_j s_ij = max(q_i*kmax, q_i*kmin)  (rank-1!)
// Mask applied AFTER softmax => denominator keeps the diagonal; diagonal
// term subtracted from the numerator only.
// ---------------------------------------------------------------------------

template <int NHG>
__device__ __forceinline__ float attn_pass(
    int h0, int i, int sl, int tid, float xi,
    const float* __restrict__ WQ, const float* __restrict__ WK,
    const float* __restrict__ WV, const float* __restrict__ W0,
    const float* hrow, float (*kln)[G], float (*vv)[G],
    float (*rmx)[4], float (*rmn)[4])
{
    // stage k*log2e and v tables; track per-head min/max of kln
    float lmx[NHG], lmn[NHG];
#pragma unroll
    for (int hh = 0; hh < NHG; ++hh) { lmx[hh] = -INFINITY; lmn[hh] = INFINITY; }

    for (int hh = 0; hh < NHG; ++hh) {
        const float* wk = WK + (size_t)(h0 + hh) * G;
        const float* wv = WV + (size_t)(h0 + hh) * G;
        for (int j = tid; j < G; j += 256) {
            float xv = hrow[j];
            float kl = xv * wk[j] * LOG2E;
            kln[hh][j] = kl;
            vv[hh][j]  = xv * wv[j];
            lmx[hh] = fmaxf(lmx[hh], kl);
            lmn[hh] = fminf(lmn[hh], kl);
        }
    }
    // wave reduce (64 lanes), then cross-wave via LDS
#pragma unroll
    for (int hh = 0; hh < NHG; ++hh) {
        for (int o = 1; o < 64; o <<= 1) {
            lmx[hh] = fmaxf(lmx[hh], __shfl_xor(lmx[hh], o));
            lmn[hh] = fminf(lmn[hh], __shfl_xor(lmn[hh], o));
        }
    }
    if ((tid & 63) == 0) {
#pragma unroll
        for (int hh = 0; hh < NHG; ++hh) {
            rmx[hh][tid >> 6] = lmx[hh];
            rmn[hh][tid >> 6] = lmn[hh];
        }
    }
    __syncthreads();

    const int isafe = (i < G) ? i : 0;
    float q[NHG], m[NHG], S1[NHG], S2[NHG];
#pragma unroll
    for (int hh = 0; hh < NHG; ++hh) {
        float kmx = fmaxf(fmaxf(rmx[hh][0], rmx[hh][1]), fmaxf(rmx[hh][2], rmx[hh][3]));
        float kmn = fminf(fminf(rmn[hh][0], rmn[hh][1]), fminf(rmn[hh][2], rmn[hh][3]));
        q[hh]  = xi * WQ[(size_t)(h0 + hh) * G + isafe];
        m[hh]  = fmaxf(q[hh] * kmx, q[hh] * kmn);   // exact row max (log2 units)
        S1[hh] = 0.f;
        S2[hh] = 0.f;
    }

    if (i < G) {
        for (int c = sl; c < NCH; c += JSL) {
#pragma unroll
            for (int hh = 0; hh < NHG; ++hh) {
                float4 kk = *reinterpret_cast<const float4*>(&kln[hh][4 * c]);
                float4 vq = *reinterpret_cast<const float4*>(&vv[hh][4 * c]);
                float e0 = __builtin_amdgcn_exp2f(fmaf(q[hh], kk.x, -m[hh]));
                float e1 = __builtin_amdgcn_exp2f(fmaf(q[hh], kk.y, -m[hh]));
                float e2 = __builtin_amdgcn_exp2f(fmaf(q[hh], kk.z, -m[hh]));
                float e3 = __builtin_amdgcn_exp2f(fmaf(q[hh], kk.w, -m[hh]));
                S1[hh] += (e0 + e1) + (e2 + e3);
                S2[hh] += (e0 * vq.x + e1 * vq.y) + (e2 * vq.z + e3 * vq.w);
            }
        }
    }

    // reduce the JSL j-slices (adjacent lanes: tid = ii*JSL + sl)
#pragma unroll
    for (int hh = 0; hh < NHG; ++hh) {
        for (int o = 1; o < JSL; o <<= 1) {
            S1[hh] += __shfl_xor(S1[hh], o);
            S2[hh] += __shfl_xor(S2[hh], o);
        }
    }

    float acc = 0.f;
    if (sl == 0 && i < G) {
#pragma unroll
        for (int hh = 0; hh < NHG; ++hh) {
            float eii = __builtin_amdgcn_exp2f(fmaf(q[hh], kln[hh][i], -m[hh]));
            acc += W0[h0 + hh] * (S2[hh] - eii * vv[hh][i]) / S1[hh];
        }
    }
    return acc;
}

__global__ __launch_bounds__(256) void attn_kernel(
    const float* __restrict__ hin, const float* __restrict__ WQ,
    const float* __restrict__ WK, const float* __restrict__ WV,
    const float* __restrict__ W0, float* __restrict__ aout)
{
    __shared__ float hrow[G];
    __shared__ float kln[3][G];
    __shared__ float vv[3][G];
    __shared__ float rmx[3][4], rmn[3][4];

    const int b   = blockIdx.y;
    const int tid = threadIdx.x;
    const int ii  = tid / JSL;
    const int sl  = tid % JSL;
    const int i   = blockIdx.x * IPB + ii;

    for (int j = tid; j < G; j += 256) hrow[j] = hin[(size_t)b * G + j];
    __syncthreads();

    const float xi = hrow[(i < G) ? i : 0];

    float acc = attn_pass<3>(0, i, sl, tid, xi, WQ, WK, WV, W0, hrow, kln, vv, rmx, rmn);
    __syncthreads();  // all reads of pass-0 tables done before overwrite
    acc += attn_pass<2>(3, i, sl, tid, xi, WQ, WK, WV, W0, hrow, kln, vv, rmx, rmn);

    if (sl == 0 && i < G) aout[(size_t)b * G + i] = acc;
}

// ---------------------------------------------------------------------------
// h_out[b,:] = base[b,:] + ln_a*(a-mean)/(std+eps) + ln_b   (std: ddof=1)
// two-pass (mean, then centered variance) for heavy-tailed a.
// ---------------------------------------------------------------------------
__global__ __launch_bounds__(256) void ln_kernel(
    const float* __restrict__ base, const float* __restrict__ a,
    const float* __restrict__ ga, const float* __restrict__ gb,
    float* __restrict__ hout)
{
    const int b   = blockIdx.x;
    const int tid = threadIdx.x;
    __shared__ float red[4];

    float s = 0.f;
    for (int j = tid; j < G; j += 256) s += a[(size_t)b * G + j];
    for (int o = 32; o; o >>= 1) s += __shfl_down(s, o);
    if ((tid & 63) == 0) red[tid >> 6] = s;
    __syncthreads();
    const float mean = ((red[0] + red[1]) + (red[2] + red[3])) / (float)G;
    __syncthreads();

    float ss = 0.f;
    for (int j = tid; j < G; j += 256) {
        float d = a[(size_t)b * G + j] - mean;
        ss += d * d;
    }
    for (int o = 32; o; o >>= 1) ss += __shfl_down(ss, o);
    if ((tid & 63) == 0) red[tid >> 6] = ss;
    __syncthreads();
    const float var = ((red[0] + red[1]) + (red[2] + red[3])) / (float)(G - 1);
    const float inv = 1.f / (sqrtf(var) + LN_EPS);

    for (int j = tid; j < G; j += 256) {
        float v = a[(size_t)b * G + j];
        hout[(size_t)b * G + j] =
            base[(size_t)b * G + j] + ga[j] * (v - mean) * inv + gb[j];
    }
}

// ---------------------------------------------------------------------------
// logits = h3 @ fc_w.T + fc_b ; out = log_softmax(logits). one block/row.
// ---------------------------------------------------------------------------
__global__ __launch_bounds__(256) void fc_kernel(
    const float* __restrict__ h, const float* __restrict__ fw,
    const float* __restrict__ fb, float* __restrict__ out)
{
    const int b   = blockIdx.x;
    const int tid = threadIdx.x;
    __shared__ float hrow[G];
    __shared__ float logits[NC];
    for (int j = tid; j < G; j += 256) hrow[j] = h[(size_t)b * G + j];
    __syncthreads();

    const int w = tid >> 6, lane = tid & 63;
    for (int c = w; c < NC; c += 4) {
        const float* wr = fw + (size_t)c * G;
        float s = 0.f;
        for (int j = lane; j < G; j += 64) s += hrow[j] * wr[j];
        for (int o = 32; o; o >>= 1) s += __shfl_down(s, o);
        if (lane == 0) logits[c] = s + fb[c];
    }
    __syncthreads();

    if (tid < 64) {
        float l = (tid < NC) ? logits[tid] : -INFINITY;
        float mm = l;
        for (int o = 32; o; o >>= 1) mm = fmaxf(mm, __shfl_xor(mm, o));
        float e = (tid < NC) ? expf(l - mm) : 0.f;
        float se = e;
        for (int o = 32; o; o >>= 1) se += __shfl_xor(se, o);
        if (tid < NC) out[(size_t)b * NC + tid] = l - mm - logf(se);
    }
}

// ---------------------------------------------------------------------------
extern "C" void kernel_launch(void* const* d_in, const int* in_sizes, int n_in,
                              void* d_out, int out_size, void* d_ws, size_t ws_size,
                              hipStream_t stream)
{
    const float* x    = (const float*)d_in[0];
    const float* WQ1  = (const float*)d_in[1];
    const float* WK1  = (const float*)d_in[2];
    const float* WV1  = (const float*)d_in[3];
    const float* W01  = (const float*)d_in[4];
    const float* WQ2  = (const float*)d_in[5];
    const float* WK2  = (const float*)d_in[6];
    const float* WV2  = (const float*)d_in[7];
    const float* W02  = (const float*)d_in[8];
    const float* WQ3  = (const float*)d_in[9];
    const float* WK3  = (const float*)d_in[10];
    const float* WV3  = (const float*)d_in[11];
    const float* W03  = (const float*)d_in[12];
    const float* ln_a = (const float*)d_in[13];
    const float* ln_b = (const float*)d_in[14];
    const float* fc_w = (const float*)d_in[15];
    const float* fc_b = (const float*)d_in[16];
    float* out = (float*)d_out;

    float* a = (float*)d_ws;          // [NB, G] attention output
    float* h = a + (size_t)NB * G;    // [NB, G] hidden state

    const dim3 agrid((G + IPB - 1) / IPB, NB);

    attn_kernel<<<agrid, 256, 0, stream>>>(x, WQ1, WK1, WV1, W01, a);
    ln_kernel<<<NB, 256, 0, stream>>>(x, a, ln_a, ln_b, h);

    attn_kernel<<<agrid, 256, 0, stream>>>(h, WQ2, WK2, WV2, W02, a);
    ln_kernel<<<NB, 256, 0, stream>>>(h, a, ln_a, ln_b, h);

    attn_kernel<<<agrid, 256, 0, stream>>>(h, WQ3, WK3, WV3, W03, a);
    ln_kernel<<<NB, 256, 0, stream>>>(h, a, ln_a, ln_b, h);

    fc_kernel<<<NB, 256, 0, stream>>>(h, fc_w, fc_b, out);
}

// Round 3
// 307.730 us; speedup vs baseline: 1.1976x; 1.1976x over previous
//
#include <hip/hip_runtime.h>
#include <math.h>

#define G      1708
#define NH     5
#define NB     16
#define NC     34
#define NCH    427          // float4 chunks per gene row (1708/4)
#define ITR    4            // i-values per thread
#define JSL    8            // j-slices per i-group
#define IPB    128          // i per block = (256/JSL)*ITR
#define LN_EPS 1e-6f
#define LOG2E  1.4426950408889634f

// ---------------------------------------------------------------------------
// Attention: out[b,i] = sum_h W0[h]*(S2 - e_ii*v_i)/S1,
//   S1 = sum_j exp2(s-m), S2 = sum_j exp2(s-m)*v_j,  s = q_i*kln_j (log2 units)
//   m_i = max(q_i*kmax, q_i*kmin)  (rank-1 score -> exact row max)
// Each thread: ITR consecutive i's x 1/JSL of j. One kk/vq LDS load feeds
// ITR q-values (4x LDS traffic reduction vs R2).
// ---------------------------------------------------------------------------

template <int NHG>
__device__ __forceinline__ void attn_pass(
    int h0, int i0, bool valid, int sl, int tid, const float4 xi4,
    const float* __restrict__ WQ, const float* __restrict__ WK,
    const float* __restrict__ WV, const float* __restrict__ W0,
    const float* hrow, float (*kln)[G], float (*vv)[G],
    float (*rmx)[4], float (*rmn)[4], float* acc)
{
    // stage k*log2e and v tables; track per-head min/max of kln
    float lmx[NHG], lmn[NHG];
#pragma unroll
    for (int hh = 0; hh < NHG; ++hh) { lmx[hh] = -INFINITY; lmn[hh] = INFINITY; }

    for (int hh = 0; hh < NHG; ++hh) {
        const float* wk = WK + (size_t)(h0 + hh) * G;
        const float* wv = WV + (size_t)(h0 + hh) * G;
        for (int j = tid; j < G; j += 256) {
            float xv = hrow[j];
            float kl = xv * wk[j] * LOG2E;
            kln[hh][j] = kl;
            vv[hh][j]  = xv * wv[j];
            lmx[hh] = fmaxf(lmx[hh], kl);
            lmn[hh] = fminf(lmn[hh], kl);
        }
    }
#pragma unroll
    for (int hh = 0; hh < NHG; ++hh) {
        for (int o = 1; o < 64; o <<= 1) {
            lmx[hh] = fmaxf(lmx[hh], __shfl_xor(lmx[hh], o));
            lmn[hh] = fminf(lmn[hh], __shfl_xor(lmn[hh], o));
        }
    }
    if ((tid & 63) == 0) {
#pragma unroll
        for (int hh = 0; hh < NHG; ++hh) {
            rmx[hh][tid >> 6] = lmx[hh];
            rmn[hh][tid >> 6] = lmn[hh];
        }
    }
    __syncthreads();

    float q[ITR][NHG], m[ITR][NHG], S1[ITR][NHG], S2[ITR][NHG];
#pragma unroll
    for (int hh = 0; hh < NHG; ++hh) {
        float kmx = fmaxf(fmaxf(rmx[hh][0], rmx[hh][1]), fmaxf(rmx[hh][2], rmx[hh][3]));
        float kmn = fminf(fminf(rmn[hh][0], rmn[hh][1]), fminf(rmn[hh][2], rmn[hh][3]));
        float4 wq4 = valid
            ? *reinterpret_cast<const float4*>(WQ + (size_t)(h0 + hh) * G + i0)
            : make_float4(0.f, 0.f, 0.f, 0.f);
        float qr[ITR] = {xi4.x * wq4.x, xi4.y * wq4.y, xi4.z * wq4.z, xi4.w * wq4.w};
#pragma unroll
        for (int r = 0; r < ITR; ++r) {
            q[r][hh]  = qr[r];
            m[r][hh]  = fmaxf(qr[r] * kmx, qr[r] * kmn);
            S1[r][hh] = 0.f;
            S2[r][hh] = 0.f;
        }
    }

    if (valid) {
        const float4* kp[NHG];
        const float4* vp[NHG];
#pragma unroll
        for (int hh = 0; hh < NHG; ++hh) {
            kp[hh] = reinterpret_cast<const float4*>(kln[hh]);
            vp[hh] = reinterpret_cast<const float4*>(vv[hh]);
        }
        for (int c = sl; c < NCH; c += JSL) {
#pragma unroll
            for (int hh = 0; hh < NHG; ++hh) {
                float4 kk = kp[hh][c];
                float4 vq = vp[hh][c];
#pragma unroll
                for (int r = 0; r < ITR; ++r) {
                    float qq = q[r][hh], mm = m[r][hh];
                    float e0 = __builtin_amdgcn_exp2f(fmaf(qq, kk.x, -mm));
                    float e1 = __builtin_amdgcn_exp2f(fmaf(qq, kk.y, -mm));
                    float e2 = __builtin_amdgcn_exp2f(fmaf(qq, kk.z, -mm));
                    float e3 = __builtin_amdgcn_exp2f(fmaf(qq, kk.w, -mm));
                    S1[r][hh] += (e0 + e1) + (e2 + e3);
                    S2[r][hh] += (e0 * vq.x + e1 * vq.y) + (e2 * vq.z + e3 * vq.w);
                }
            }
        }
    }

    // reduce JSL j-slices (same i-group = adjacent lanes: tid = ig*JSL + sl)
#pragma unroll
    for (int r = 0; r < ITR; ++r)
#pragma unroll
        for (int hh = 0; hh < NHG; ++hh) {
            for (int o = 1; o < JSL; o <<= 1) {
                S1[r][hh] += __shfl_xor(S1[r][hh], o);
                S2[r][hh] += __shfl_xor(S2[r][hh], o);
            }
        }

    if (sl == 0 && valid) {
#pragma unroll
        for (int r = 0; r < ITR; ++r) {
            int i = i0 + r;
#pragma unroll
            for (int hh = 0; hh < NHG; ++hh) {
                float eii = __builtin_amdgcn_exp2f(fmaf(q[r][hh], kln[hh][i], -m[r][hh]));
                acc[r] += W0[h0 + hh] * (S2[r][hh] - eii * vv[hh][i]) / S1[r][hh];
            }
        }
    }
}

__global__ __launch_bounds__(256) void attn_kernel(
    const float* __restrict__ hin, const float* __restrict__ WQ,
    const float* __restrict__ WK, const float* __restrict__ WV,
    const float* __restrict__ W0, float* __restrict__ aout)
{
    __shared__ float hrow[G];
    __shared__ float kln[3][G];
    __shared__ float vv[3][G];
    __shared__ float rmx[3][4], rmn[3][4];

    const int b   = blockIdx.y;
    const int tid = threadIdx.x;
    const int ig  = tid / JSL;
    const int sl  = tid % JSL;
    const int i0  = blockIdx.x * IPB + ig * ITR;   // multiple of 4
    const bool valid = (i0 + ITR) <= G;            // G%4==0 -> all-or-nothing

    for (int j = tid; j < G; j += 256) hrow[j] = hin[(size_t)b * G + j];
    __syncthreads();

    const float4 xi4 = valid ? *reinterpret_cast<const float4*>(&hrow[i0])
                             : make_float4(0.f, 0.f, 0.f, 0.f);

    float acc[ITR] = {0.f, 0.f, 0.f, 0.f};
    attn_pass<3>(0, i0, valid, sl, tid, xi4, WQ, WK, WV, W0, hrow, kln, vv, rmx, rmn, acc);
    __syncthreads();  // pass-0 table reads complete before overwrite
    attn_pass<2>(3, i0, valid, sl, tid, xi4, WQ, WK, WV, W0, hrow, kln, vv, rmx, rmn, acc);

    if (sl == 0 && valid)
        *reinterpret_cast<float4*>(aout + (size_t)b * G + i0) =
            make_float4(acc[0], acc[1], acc[2], acc[3]);
}

// ---------------------------------------------------------------------------
// h_out = base + ln_a*(a-mean)/(std+eps) + ln_b   (ddof=1, two-pass)
// ---------------------------------------------------------------------------
__global__ __launch_bounds__(256) void ln_kernel(
    const float* __restrict__ base, const float* __restrict__ a,
    const float* __restrict__ ga, const float* __restrict__ gb,
    float* __restrict__ hout)
{
    const int b   = blockIdx.x;
    const int tid = threadIdx.x;
    __shared__ float red[4];

    float s = 0.f;
    for (int j = tid; j < G; j += 256) s += a[(size_t)b * G + j];
    for (int o = 32; o; o >>= 1) s += __shfl_down(s, o);
    if ((tid & 63) == 0) red[tid >> 6] = s;
    __syncthreads();
    const float mean = ((red[0] + red[1]) + (red[2] + red[3])) / (float)G;
    __syncthreads();

    float ss = 0.f;
    for (int j = tid; j < G; j += 256) {
        float d = a[(size_t)b * G + j] - mean;
        ss += d * d;
    }
    for (int o = 32; o; o >>= 1) ss += __shfl_down(ss, o);
    if ((tid & 63) == 0) red[tid >> 6] = ss;
    __syncthreads();
    const float var = ((red[0] + red[1]) + (red[2] + red[3])) / (float)(G - 1);
    const float inv = 1.f / (sqrtf(var) + LN_EPS);

    for (int j = tid; j < G; j += 256) {
        float v = a[(size_t)b * G + j];
        hout[(size_t)b * G + j] =
            base[(size_t)b * G + j] + ga[j] * (v - mean) * inv + gb[j];
    }
}

// ---------------------------------------------------------------------------
// logits[b,c] = h[b,:]·fw[c,:] + fb[c] — one wave per (c,b), float4 loads
// ---------------------------------------------------------------------------
__global__ __launch_bounds__(64) void logits_kernel(
    const float* __restrict__ h, const float* __restrict__ fw,
    const float* __restrict__ fb, float* __restrict__ logits)
{
    const int c = blockIdx.x, b = blockIdx.y;
    const int lane = threadIdx.x;
    const float4* h4 = reinterpret_cast<const float4*>(h + (size_t)b * G);
    const float4* w4 = reinterpret_cast<const float4*>(fw + (size_t)c * G);
    float s = 0.f;
    for (int k = lane; k < NCH; k += 64) {
        float4 a = h4[k], w = w4[k];
        s += (a.x * w.x + a.y * w.y) + (a.z * w.z + a.w * w.w);
    }
    for (int o = 32; o; o >>= 1) s += __shfl_down(s, o);
    if (lane == 0) logits[(size_t)b * NC + c] = s + fb[c];
}

// out = log_softmax(logits) — one wave per batch row
__global__ __launch_bounds__(64) void lsm_kernel(
    const float* __restrict__ logits, float* __restrict__ out)
{
    const int b = blockIdx.x, tid = threadIdx.x;
    float l = (tid < NC) ? logits[(size_t)b * NC + tid] : -INFINITY;
    float mm = l;
    for (int o = 32; o; o >>= 1) mm = fmaxf(mm, __shfl_xor(mm, o));
    float e = (tid < NC) ? expf(l - mm) : 0.f;
    float se = e;
    for (int o = 32; o; o >>= 1) se += __shfl_xor(se, o);
    if (tid < NC) out[(size_t)b * NC + tid] = l - mm - logf(se);
}

// ---------------------------------------------------------------------------
extern "C" void kernel_launch(void* const* d_in, const int* in_sizes, int n_in,
                              void* d_out, int out_size, void* d_ws, size_t ws_size,
                              hipStream_t stream)
{
    const float* x    = (const float*)d_in[0];
    const float* WQ1  = (const float*)d_in[1];
    const float* WK1  = (const float*)d_in[2];
    const float* WV1  = (const float*)d_in[3];
    const float* W01  = (const float*)d_in[4];
    const float* WQ2  = (const float*)d_in[5];
    const float* WK2  = (const float*)d_in[6];
    const float* WV2  = (const float*)d_in[7];
    const float* W02  = (const float*)d_in[8];
    const float* WQ3  = (const float*)d_in[9];
    const float* WK3  = (const float*)d_in[10];
    const float* WV3  = (const float*)d_in[11];
    const float* W03  = (const float*)d_in[12];
    const float* ln_a = (const float*)d_in[13];
    const float* ln_b = (const float*)d_in[14];
    const float* fc_w = (const float*)d_in[15];
    const float* fc_b = (const float*)d_in[16];
    float* out = (float*)d_out;

    float* a      = (float*)d_ws;               // [NB, G]
    float* h      = a + (size_t)NB * G;         // [NB, G]
    float* logits = h + (size_t)NB * G;         // [NB, NC]

    const dim3 agrid((G + IPB - 1) / IPB, NB);  // (14, 16)

    attn_kernel<<<agrid, 256, 0, stream>>>(x, WQ1, WK1, WV1, W01, a);
    ln_kernel<<<NB, 256, 0, stream>>>(x, a, ln_a, ln_b, h);

    attn_kernel<<<agrid, 256, 0, stream>>>(h, WQ2, WK2, WV2, W02, a);
    ln_kernel<<<NB, 256, 0, stream>>>(h, a, ln_a, ln_b, h);

    attn_kernel<<<agrid, 256, 0, stream>>>(h, WQ3, WK3, WV3, W03, a);
    ln_kernel<<<NB, 256, 0, stream>>>(h, a, ln_a, ln_b, h);

    logits_kernel<<<dim3(NC, NB), 64, 0, stream>>>(h, fc_w, fc_b, logits);
    lsm_kernel<<<NB, 64, 0, stream>>>(logits, out);
}

// Round 4
// 264.133 us; speedup vs baseline: 1.3953x; 1.1651x over previous
//
#include <hip/hip_runtime.h>
#include <math.h>

#define G      1708
#define NH     5
#define NB     16
#define NC     34
#define NCH    427          // float4 chunks per gene row
#define JB     7            // j-chunks (blocks) per row;  G = JB*JCH
#define JCH    244          // j-values per chunk
#define CH4    61           // float4 chunks per j-chunk
#define JSL    8            // j-slices (threads) per i-group
#define ITR    2            // i-values per thread
#define IPB    64           // i per block = (256/JSL)*ITR
#define IBLK   27           // ceil(G/IPB)
#define LN_EPS 1e-6f
#define LOG2E  1.4426950408889634f

// ---------------------------------------------------------------------------
// Rank-1 score trick: s_ij = q_i*k_j  =>  row max m_i = max(q_i*kmax, q_i*kmin)
// with kmax/kmin global per (b,h). Hence partial softmax sums over j-chunks
// computed with the SAME m_i are directly addable across blocks.
// ---------------------------------------------------------------------------

// block-wide min/max reduce of NH pairs, write kmm[b][h][2]
__device__ __forceinline__ void block_minmax_write(
    float* lmx, float* lmn, float* __restrict__ kmm, int b, int tid)
{
    __shared__ float rmx[NH][4], rmn[NH][4];
#pragma unroll
    for (int h = 0; h < NH; ++h)
        for (int o = 1; o < 64; o <<= 1) {
            lmx[h] = fmaxf(lmx[h], __shfl_xor(lmx[h], o));
            lmn[h] = fminf(lmn[h], __shfl_xor(lmn[h], o));
        }
    if ((tid & 63) == 0) {
#pragma unroll
        for (int h = 0; h < NH; ++h) {
            rmx[h][tid >> 6] = lmx[h];
            rmn[h][tid >> 6] = lmn[h];
        }
    }
    __syncthreads();
    if (tid < NH) {
        float mx = fmaxf(fmaxf(rmx[tid][0], rmx[tid][1]), fmaxf(rmx[tid][2], rmx[tid][3]));
        float mn = fminf(fminf(rmn[tid][0], rmn[tid][1]), fminf(rmn[tid][2], rmn[tid][3]));
        kmm[(b * NH + tid) * 2 + 0] = mx;
        kmm[(b * NH + tid) * 2 + 1] = mn;
    }
}

// standalone min/max of kln = hin*WK*log2e  (used for layer-1 input x)
__global__ __launch_bounds__(256) void minmax_kernel(
    const float* __restrict__ hin, const float* __restrict__ WK,
    float* __restrict__ kmm)
{
    const int b = blockIdx.x, tid = threadIdx.x;
    float lmx[NH], lmn[NH];
#pragma unroll
    for (int h = 0; h < NH; ++h) { lmx[h] = -INFINITY; lmn[h] = INFINITY; }
    for (int j = tid; j < G; j += 256) {
        float xv = hin[(size_t)b * G + j];
#pragma unroll
        for (int h = 0; h < NH; ++h) {
            float kl = xv * WK[(size_t)h * G + j] * LOG2E;
            lmx[h] = fmaxf(lmx[h], kl);
            lmn[h] = fminf(lmn[h], kl);
        }
    }
    block_minmax_write(lmx, lmn, kmm, b, tid);
}

// ---------------------------------------------------------------------------
// Partial softmax sums for one j-chunk:
//   S1p[b,jb,h,i] = sum_{j in chunk} exp2(q_i*kln_j - m_i)
//   S2p[b,jb,h,i] = sum_{j in chunk} exp2(q_i*kln_j - m_i) * v_j
// grid (27, 7, 16), 256 threads, 9.5 KB LDS -> ~6 blocks/CU.
// ---------------------------------------------------------------------------
__global__ __launch_bounds__(256) void attn_partial(
    const float* __restrict__ hin, const float* __restrict__ WQ,
    const float* __restrict__ WK, const float* __restrict__ WV,
    const float* __restrict__ kmm,
    float* __restrict__ S1p, float* __restrict__ S2p)
{
    __shared__ float kc[NH][JCH];
    __shared__ float vc[NH][JCH];

    const int b = blockIdx.z, jb = blockIdx.y;
    const int tid = threadIdx.x;
    const int jg = jb * JCH;

    for (int idx = tid; idx < NH * JCH; idx += 256) {
        int h = idx / JCH, jj = idx - h * JCH;
        float xv = hin[(size_t)b * G + jg + jj];
        kc[h][jj] = xv * WK[(size_t)h * G + jg + jj] * LOG2E;
        vc[h][jj] = xv * WV[(size_t)h * G + jg + jj];
    }
    __syncthreads();

    const int ig = tid / JSL, sl = tid % JSL;
    const int i0 = blockIdx.x * IPB + ig * ITR;
    const bool valid = i0 < G;              // G even, i0 even -> all-or-nothing
    const int is = valid ? i0 : 0;

    const float2 xi2 = *reinterpret_cast<const float2*>(hin + (size_t)b * G + is);

    float q[ITR][NH], m[ITR][NH], S1[ITR][NH], S2[ITR][NH];
#pragma unroll
    for (int h = 0; h < NH; ++h) {
        float kx = kmm[(b * NH + h) * 2 + 0];
        float kn = kmm[(b * NH + h) * 2 + 1];
        float2 wq = *reinterpret_cast<const float2*>(WQ + (size_t)h * G + is);
        q[0][h] = xi2.x * wq.x;
        q[1][h] = xi2.y * wq.y;
#pragma unroll
        for (int r = 0; r < ITR; ++r) {
            m[r][h]  = fmaxf(q[r][h] * kx, q[r][h] * kn);
            S1[r][h] = 0.f;
            S2[r][h] = 0.f;
        }
    }

    for (int c = sl; c < CH4; c += JSL) {
#pragma unroll
        for (int h = 0; h < NH; ++h) {
            float4 kk = reinterpret_cast<const float4*>(kc[h])[c];
            float4 vq = reinterpret_cast<const float4*>(vc[h])[c];
#pragma unroll
            for (int r = 0; r < ITR; ++r) {
                float qq = q[r][h], mm = m[r][h];
                float e0 = __builtin_amdgcn_exp2f(fmaf(qq, kk.x, -mm));
                float e1 = __builtin_amdgcn_exp2f(fmaf(qq, kk.y, -mm));
                float e2 = __builtin_amdgcn_exp2f(fmaf(qq, kk.z, -mm));
                float e3 = __builtin_amdgcn_exp2f(fmaf(qq, kk.w, -mm));
                S1[r][h] += (e0 + e1) + (e2 + e3);
                S2[r][h] += (e0 * vq.x + e1 * vq.y) + (e2 * vq.z + e3 * vq.w);
            }
        }
    }

#pragma unroll
    for (int r = 0; r < ITR; ++r)
#pragma unroll
        for (int h = 0; h < NH; ++h)
            for (int o = 1; o < JSL; o <<= 1) {
                S1[r][h] += __shfl_xor(S1[r][h], o);
                S2[r][h] += __shfl_xor(S2[r][h], o);
            }

    if (sl == 0 && valid) {
#pragma unroll
        for (int h = 0; h < NH; ++h) {
            size_t base = ((size_t)(b * JB + jb) * NH + h) * G + i0;
            *reinterpret_cast<float2*>(S1p + base) = make_float2(S1[0][h], S1[1][h]);
            *reinterpret_cast<float2*>(S2p + base) = make_float2(S2[0][h], S2[1][h]);
        }
    }
}

// ---------------------------------------------------------------------------
// Combine partials + diagonal correction:
//   out[b,i] = sum_h W0[h]*(S2 - e_ii*v_i)/S1
// ---------------------------------------------------------------------------
__global__ __launch_bounds__(256) void attn_combine(
    const float* __restrict__ hin, const float* __restrict__ WQ,
    const float* __restrict__ WK, const float* __restrict__ WV,
    const float* __restrict__ W0, const float* __restrict__ kmm,
    const float* __restrict__ S1p, const float* __restrict__ S2p,
    float* __restrict__ aout)
{
    const int b = blockIdx.y;
    const int i = blockIdx.x * 256 + threadIdx.x;
    if (i >= G) return;
    const float xi = hin[(size_t)b * G + i];
    float acc = 0.f;
#pragma unroll
    for (int h = 0; h < NH; ++h) {
        float S1 = 0.f, S2 = 0.f;
#pragma unroll
        for (int jb = 0; jb < JB; ++jb) {
            size_t base = ((size_t)(b * JB + jb) * NH + h) * G + i;
            S1 += S1p[base];
            S2 += S2p[base];
        }
        float q   = xi * WQ[(size_t)h * G + i];
        float kli = xi * WK[(size_t)h * G + i] * LOG2E;
        float vvi = xi * WV[(size_t)h * G + i];
        float kx  = kmm[(b * NH + h) * 2 + 0];
        float kn  = kmm[(b * NH + h) * 2 + 1];
        float mm  = fmaxf(q * kx, q * kn);
        float eii = __builtin_amdgcn_exp2f(fmaf(q, kli, -mm));
        acc += W0[h] * (S2 - eii * vvi) / S1;
    }
    aout[(size_t)b * G + i] = acc;
}

// ---------------------------------------------------------------------------
// h_out = base + ln_a*(a-mean)/(std+eps) + ln_b  (ddof=1, two-pass),
// fused with next layer's per-(b,h) kln min/max.
// ---------------------------------------------------------------------------
__global__ __launch_bounds__(256) void ln_minmax_kernel(
    const float* __restrict__ base, const float* __restrict__ a,
    const float* __restrict__ ga, const float* __restrict__ gb,
    float* __restrict__ hout, const float* __restrict__ WKn,
    float* __restrict__ kmm_next)
{
    const int b = blockIdx.x;
    const int tid = threadIdx.x;
    __shared__ float red[4];

    float s = 0.f;
    for (int j = tid; j < G; j += 256) s += a[(size_t)b * G + j];
    for (int o = 32; o; o >>= 1) s += __shfl_down(s, o);
    if ((tid & 63) == 0) red[tid >> 6] = s;
    __syncthreads();
    const float mean = ((red[0] + red[1]) + (red[2] + red[3])) / (float)G;
    __syncthreads();

    float ss = 0.f;
    for (int j = tid; j < G; j += 256) {
        float d = a[(size_t)b * G + j] - mean;
        ss += d * d;
    }
    for (int o = 32; o; o >>= 1) ss += __shfl_down(ss, o);
    if ((tid & 63) == 0) red[tid >> 6] = ss;
    __syncthreads();
    const float var = ((red[0] + red[1]) + (red[2] + red[3])) / (float)(G - 1);
    const float inv = 1.f / (sqrtf(var) + LN_EPS);

    float lmx[NH], lmn[NH];
#pragma unroll
    for (int h = 0; h < NH; ++h) { lmx[h] = -INFINITY; lmn[h] = INFINITY; }

    for (int j = tid; j < G; j += 256) {
        float v  = a[(size_t)b * G + j];
        float hv = base[(size_t)b * G + j] + ga[j] * (v - mean) * inv + gb[j];
        hout[(size_t)b * G + j] = hv;
#pragma unroll
        for (int h = 0; h < NH; ++h) {
            float kl = hv * WKn[(size_t)h * G + j] * LOG2E;
            lmx[h] = fmaxf(lmx[h], kl);
            lmn[h] = fminf(lmn[h], kl);
        }
    }
    __syncthreads();
    block_minmax_write(lmx, lmn, kmm_next, b, tid);
}

// ---------------------------------------------------------------------------
__global__ __launch_bounds__(64) void logits_kernel(
    const float* __restrict__ h, const float* __restrict__ fw,
    const float* __restrict__ fb, float* __restrict__ logits)
{
    const int c = blockIdx.x, b = blockIdx.y;
    const int lane = threadIdx.x;
    const float4* h4 = reinterpret_cast<const float4*>(h + (size_t)b * G);
    const float4* w4 = reinterpret_cast<const float4*>(fw + (size_t)c * G);
    float s = 0.f;
    for (int k = lane; k < NCH; k += 64) {
        float4 av = h4[k], w = w4[k];
        s += (av.x * w.x + av.y * w.y) + (av.z * w.z + av.w * w.w);
    }
    for (int o = 32; o; o >>= 1) s += __shfl_down(s, o);
    if (lane == 0) logits[(size_t)b * NC + c] = s + fb[c];
}

__global__ __launch_bounds__(64) void lsm_kernel(
    const float* __restrict__ logits, float* __restrict__ out)
{
    const int b = blockIdx.x, tid = threadIdx.x;
    float l = (tid < NC) ? logits[(size_t)b * NC + tid] : -INFINITY;
    float mm = l;
    for (int o = 32; o; o >>= 1) mm = fmaxf(mm, __shfl_xor(mm, o));
    float e = (tid < NC) ? expf(l - mm) : 0.f;
    float se = e;
    for (int o = 32; o; o >>= 1) se += __shfl_xor(se, o);
    if (tid < NC) out[(size_t)b * NC + tid] = l - mm - logf(se);
}

// ---------------------------------------------------------------------------
extern "C" void kernel_launch(void* const* d_in, const int* in_sizes, int n_in,
                              void* d_out, int out_size, void* d_ws, size_t ws_size,
                              hipStream_t stream)
{
    const float* x    = (const float*)d_in[0];
    const float* WQ1  = (const float*)d_in[1];
    const float* WK1  = (const float*)d_in[2];
    const float* WV1  = (const float*)d_in[3];
    const float* W01  = (const float*)d_in[4];
    const float* WQ2  = (const float*)d_in[5];
    const float* WK2  = (const float*)d_in[6];
    const float* WV2  = (const float*)d_in[7];
    const float* W02  = (const float*)d_in[8];
    const float* WQ3  = (const float*)d_in[9];
    const float* WK3  = (const float*)d_in[10];
    const float* WV3  = (const float*)d_in[11];
    const float* W03  = (const float*)d_in[12];
    const float* ln_a = (const float*)d_in[13];
    const float* ln_b = (const float*)d_in[14];
    const float* fc_w = (const float*)d_in[15];
    const float* fc_b = (const float*)d_in[16];
    float* out = (float*)d_out;

    float* a      = (float*)d_ws;                      // [NB,G]
    float* h      = a + (size_t)NB * G;                // [NB,G]
    float* logits = h + (size_t)NB * G;                // [NB,NC]
    float* kmm    = logits + (size_t)NB * NC;          // 4 slots x [NB,NH,2]
    float* S1p    = kmm + 4 * NB * NH * 2;             // [NB,JB,NH,G]
    float* S2p    = S1p + (size_t)NB * JB * NH * G;    // [NB,JB,NH,G]

    const int KS = NB * NH * 2;                        // kmm slot stride
    const dim3 pgrid(IBLK, JB, NB);                    // (27,7,16)=3024 blocks
    const dim3 cgrid((G + 255) / 256, NB);             // (7,16)

    minmax_kernel<<<NB, 256, 0, stream>>>(x, WK1, kmm);
    attn_partial<<<pgrid, 256, 0, stream>>>(x, WQ1, WK1, WV1, kmm, S1p, S2p);
    attn_combine<<<cgrid, 256, 0, stream>>>(x, WQ1, WK1, WV1, W01, kmm, S1p, S2p, a);
    ln_minmax_kernel<<<NB, 256, 0, stream>>>(x, a, ln_a, ln_b, h, WK2, kmm + KS);

    attn_partial<<<pgrid, 256, 0, stream>>>(h, WQ2, WK2, WV2, kmm + KS, S1p, S2p);
    attn_combine<<<cgrid, 256, 0, stream>>>(h, WQ2, WK2, WV2, W02, kmm + KS, S1p, S2p, a);
    ln_minmax_kernel<<<NB, 256, 0, stream>>>(h, a, ln_a, ln_b, h, WK3, kmm + 2 * KS);

    attn_partial<<<pgrid, 256, 0, stream>>>(h, WQ3, WK3, WV3, kmm + 2 * KS, S1p, S2p);
    attn_combine<<<cgrid, 256, 0, stream>>>(h, WQ3, WK3, WV3, W03, kmm + 2 * KS, S1p, S2p, a);
    ln_minmax_kernel<<<NB, 256, 0, stream>>>(h, a, ln_a, ln_b, h, WK1, kmm + 3 * KS);

    logits_kernel<<<dim3(NC, NB), 64, 0, stream>>>(h, fc_w, fc_b, logits);
    lsm_kernel<<<NB, 64, 0, stream>>>(logits, out);
}